// Round 8
// baseline (15.771 us; speedup 1.0000x reference)
//
#include <hip/hip_runtime.h>
#include <hip/hip_bf16.h>

#define NGRID  2048
#define BATCH  4
#define CIN    16
#define COUT   32
#define NOUT   1024
#define NT     8                      // targets per block (B cols 8-15 duplicate 0-7)
#define NW     16                     // waves per block = K slices
#define KSL    (NGRID / NW)           // 128 grid points per wave
#define KSTEP  (KSL / 32)             // 4 MFMA K-steps per wave
#define NBLK   (BATCH * (NOUT / NT))  // 512 blocks -> 2 blocks/CU (VGPR<=64)

typedef short bf16x8 __attribute__((ext_vector_type(8)));
typedef float f32x4  __attribute__((ext_vector_type(4)));

__device__ __forceinline__ float fexp2(float x) {
#if __has_builtin(__builtin_amdgcn_exp2f)
    return __builtin_amdgcn_exp2f(x);
#else
    return exp2f(x);
#endif
}

union ABfrag { bf16x8 v; short2 s2[4]; };

__device__ __forceinline__ short2 pk_bf16(float lo, float hi) {
    __hip_bfloat162 h = __float22bfloat162_rn(float2{lo, hi});
    short2 r;
    __builtin_memcpy(&r, &h, 4);
    return r;
}

// Block = (batch, 8 targets), 16 waves; wave wv owns grid K-slice [wv*128, wv*128+128).
// z = r_bf16 @ w_bf16 via mfma_f32_16x16x32_bf16 (uniform-sigma fast path).
//   A: row c = lane&15, k = (lane>>4)*8 + j ; B: col = lane&15 -> target (col&7)
//   C/D (m89-verified): col = lane&15, row c = (lane>>4)*4 + reg
// R5 ordering kept (loads in-loop, minmax loads first). 2 blocks/CU for barrier overlap.
__global__ __launch_bounds__(1024, 8) void conv_decoder_mfma(
        const float* __restrict__ r,      // (B, CIN, NGRID)
        const float* __restrict__ xc,     // (B*NCTX) = 1024 floats
        const float* __restrict__ xt,     // (B*NOUT) = 4096 floats
        const float* __restrict__ sigma,  // (CIN)
        const float* __restrict__ W,      // (CIN, COUT)
        const float* __restrict__ bias,   // (COUT)
        float* __restrict__ out) {        // (B, NOUT, COUT)
    const int tid  = threadIdx.x;
    const int lane = tid & 63;
    const int wv   = tid >> 6;            // 0..15 = K slice
    const int blk  = blockIdx.x;
    const int b    = blk >> 7;            // 128 target-groups per batch
    const int tg0  = (blk & 127) * NT;

    __shared__ float part[NW][CIN][16];   // 16 KB (cols 8-15 duplicate)
    __shared__ float zbuf[CIN][NT];
    __shared__ float smn[NW], smx[NW];

    // ---- block-wide min/max over xc (1024) + xt (4096) ----
    float mn, mx;
    {
        float v = xc[tid];
        mn = v; mx = v;
        float4 u = *reinterpret_cast<const float4*>(xt + tid * 4);
        mn = fminf(mn, fminf(fminf(u.x, u.y), fminf(u.z, u.w)));
        mx = fmaxf(mx, fmaxf(fmaxf(u.x, u.y), fmaxf(u.z, u.w)));
        #pragma unroll
        for (int off = 32; off; off >>= 1) {
            mn = fminf(mn, __shfl_xor(mn, off));
            mx = fmaxf(mx, __shfl_xor(mx, off));
        }
    }
    if (lane == 0) { smn[wv] = mn; smx[wv] = mx; }

    // ---- uniformity check on raw sigma (exp monotone => equivalent), 1 live reg ----
    const float sg0 = sigma[0];
    bool uni = true;
    #pragma unroll
    for (int c = 1; c < CIN; ++c) uni = uni && (sigma[c] == sg0);

    __syncthreads();
    #pragma unroll
    for (int w2 = 0; w2 < NW; ++w2) {
        mn = fminf(mn, smn[w2]);
        mx = fmaxf(mx, smx[w2]);
    }
    const float xmin = mn - 0.1f;
    const float step = ((mx + 0.1f) - xmin) * (1.0f / (float)(NGRID - 1));

    const int t   = lane & 15;            // B/C col; channel row for A
    const int kb  = lane >> 4;            // k-group
    const int wk0 = wv * KSL;
    const float xT = xt[b * NOUT + tg0 + (t & (NT - 1))];
    const float* rb = r + (size_t)b * (CIN * NGRID);

    f32x4 acc = {0.0f, 0.0f, 0.0f, 0.0f};

    const float LOG2E = 1.4426950408889634f;
    if (uni) {
        // w = exp2(-(s*g - s*x)^2), s = sqrt(0.5*LOG2E)/scale = sqrt(0.5*LOG2E)*exp2(-LOG2E*sg0)
        const float s     = 0.8493218002880191f * fexp2(-LOG2E * sg0);
        const float sxm   = s * xmin;
        const float sstep = s * step;
        const float sx    = s * xT;
        const float* rrow = rb + t * NGRID + wk0 + kb * 8;

        #pragma unroll
        for (int kk = 0; kk < KSTEP; ++kk) {
            const int k0 = wk0 + kk * 32;
            float4 r0 = *reinterpret_cast<const float4*>(rrow + kk * 32);
            float4 r1 = *reinterpret_cast<const float4*>(rrow + kk * 32 + 4);
            ABfrag A;
            A.s2[0] = pk_bf16(r0.x, r0.y);
            A.s2[1] = pk_bf16(r0.z, r0.w);
            A.s2[2] = pk_bf16(r1.x, r1.y);
            A.s2[3] = pk_bf16(r1.z, r1.w);
            float wgt[8];
            #pragma unroll
            for (int j = 0; j < 8; ++j) {
                float gi = (float)(k0 + kb * 8 + j);
                float d  = __builtin_fmaf(sstep, gi, sxm) - sx;
                wgt[j] = fexp2(-(d * d));
            }
            ABfrag Bf;
            #pragma unroll
            for (int p = 0; p < 4; ++p)
                Bf.s2[p] = pk_bf16(wgt[2 * p], wgt[2 * p + 1]);
            acc = __builtin_amdgcn_mfma_f32_16x16x32_bf16(A.v, Bf.v, acc, 0, 0, 0);
        }
    } else {
        // generic per-channel-sigma fallback (f32 VALU), same C-frag layout
        float a2[CIN];
        #pragma unroll
        for (int c = 0; c < CIN; ++c)
            a2[c] = -0.5f * LOG2E * fexp2(-2.0f * LOG2E * sigma[c]);
        #pragma unroll 1
        for (int k = 0; k < KSL; ++k) {
            float g  = xmin + step * (float)(wk0 + k);
            float d  = g - xT;
            float d2 = d * d;
            #pragma unroll
            for (int reg = 0; reg < 4; ++reg) {
                int c = kb * 4 + reg;
                acc[reg] += rb[c * NGRID + wk0 + k] * fexp2(a2[c] * d2);
            }
        }
    }

    // ---- write C fragments; cross-wave K reduction ----
    #pragma unroll
    for (int reg = 0; reg < 4; ++reg)
        part[wv][kb * 4 + reg][t] = acc[reg];
    __syncthreads();

    if (tid < CIN * NT) {                 // 128 threads: one (c,t) each
        const int c  = tid >> 3;
        const int tt = tid & (NT - 1);
        float z = 0.0f;
        #pragma unroll
        for (int w2 = 0; w2 < NW; ++w2) z += part[w2][c][tt];
        zbuf[c][tt] = z;
    }
    __syncthreads();

    // ---- epilogue: 256 threads, one (t, cout) each ----
    if (tid < NT * COUT) {
        const int tt = tid >> 5;
        const int co = tid & 31;
        float o = bias[co];
        #pragma unroll
        for (int c = 0; c < CIN; ++c)
            o = __builtin_fmaf(zbuf[c][tt], W[c * COUT + co], o);
        out[((size_t)b * NOUT + tg0 + tt) * COUT + co] = o;
    }
}

extern "C" void kernel_launch(void* const* d_in, const int* in_sizes, int n_in,
                              void* d_out, int out_size, void* d_ws, size_t ws_size,
                              hipStream_t stream) {
    const float* r  = (const float*)d_in[0];  // (4,16,2048)
    const float* xc = (const float*)d_in[1];  // (4,256,1)
    // d_in[2] = y_context — unused by the reference
    const float* xt = (const float*)d_in[3];  // (4,1024,1)
    const float* sg = (const float*)d_in[4];  // (16)
    const float* W  = (const float*)d_in[5];  // (16,32)
    const float* bs = (const float*)d_in[6];  // (32)
    float* out = (float*)d_out;               // (4,1024,32) f32

    conv_decoder_mfma<<<NBLK, 1024, 0, stream>>>(r, xc, xt, sg, W, bs, out);
}